// Round 11
// baseline (695.785 us; speedup 1.0000x reference)
//
#include <hip/hip_runtime.h>

// Decoder: y,hn -> h0 -> gx -> 128-step GRU -> logits.  All kernels on `stream`.
// R11: fused scan+projection, projection B-panels made LDS-RESIDENT.
// Blocks 0..15: persistent GRU scan (16 publishers, 4 waves, LLC sc0sc1
// exchange -- R8's proven protocol, untouched). Blocks 16..255: static
// column-panel assignment tn=bid-16 (bids 16..25 also cover tn 240..249);
// B panel (128x512 bf16 = 131KB) staged into LDS ONCE, then tm=0..15 walked
// pipelined behind the scan (probe gate + sentinel-polled A staging).
// R10's 287MB FETCH (16x pred_w re-read, L2 thrash) -> pred_w read once.

typedef __attribute__((ext_vector_type(8))) short           bf8_t;   // MFMA A/B frag (8 bf16)
typedef __attribute__((ext_vector_type(8))) unsigned short  us8_t;
typedef __attribute__((ext_vector_type(4))) unsigned short  us4_t;
typedef __attribute__((ext_vector_type(4))) float           f4_t;    // MFMA C/D frag
typedef __attribute__((ext_vector_type(4))) unsigned int    u4_t;

#define SENT 0xFFFFFFFFu   // two 0xFFFF bf16 (-NaN): unreachable from finite math

__device__ __forceinline__ unsigned short f2bf(float x) {   // RNE fp32->bf16
    unsigned u = __builtin_bit_cast(unsigned, x);
    u += 0x7FFFu + ((u >> 16) & 1u);
    return (unsigned short)(u >> 16);
}
// fast gates: v_exp + v_rcp (~1-2 ulp) -- far below bf16 output granularity
__device__ __forceinline__ float fsigm(float x) {
    return __builtin_amdgcn_rcpf(1.f + __expf(-x));
}
__device__ __forceinline__ float ftanh(float x) {           // (e^2x-1)/(e^2x+1)
    float e = __expf(2.f * x);                              // 0->-1, inf->+1: safe
    return 1.f - 2.f * __builtin_amdgcn_rcpf(e + 1.f);
}

__device__ __forceinline__ bf8_t mk_frag(f4_t v0, f4_t v1) {
    bf8_t f;
    f[0] = (short)f2bf(v0[0]); f[1] = (short)f2bf(v0[1]);
    f[2] = (short)f2bf(v0[2]); f[3] = (short)f2bf(v0[3]);
    f[4] = (short)f2bf(v1[0]); f[5] = (short)f2bf(v1[1]);
    f[6] = (short)f2bf(v1[2]); f[7] = (short)f2bf(v1[3]);
    return f;
}

// ---- LLC-coherent (sc0 sc1 = bypass L1+L2, hit coherence point) accessors ----
__device__ __forceinline__ void llc_store_u32(unsigned int* p, unsigned int v) {
    asm volatile("global_store_dword %0, %1, off sc0 sc1" :: "v"(p), "v"(v) : "memory");
}

// ---------------- sentinel fill: hbuf + HoutP ----------------
__global__ void k_fill(unsigned int* __restrict__ hbuf, unsigned int* __restrict__ hout) {
    int i = blockIdx.x * blockDim.x + threadIdx.x;   // 263168 u4s total
    u4_t v = {SENT, SENT, SENT, SENT};
    if (i < 132096) ((u4_t*)hbuf)[i] = v;            // 129*4096 dwords
    else            ((u4_t*)hout)[i - 132096] = v;   // 2048*256 dwords
}

// ---------------- bulk fp32 -> bf16 ----------------
__global__ void k_conv(const float* __restrict__ src, unsigned short* __restrict__ dst, int n4) {
    int i = blockIdx.x * blockDim.x + threadIdx.x;
    int stride = gridDim.x * blockDim.x;
    for (; i < n4; i += stride) {
        f4_t v = ((const f4_t*)src)[i];
        us4_t o;
        o[0] = f2bf(v[0]); o[1] = f2bf(v[1]); o[2] = f2bf(v[2]); o[3] = f2bf(v[3]);
        ((us4_t*)dst)[i] = o;
    }
}

// ---------------- x = bf16(emb[y]) ----------------
__global__ void k_gather(const int* __restrict__ y, const float* __restrict__ emb,
                         unsigned short* __restrict__ xbf) {
    int m = blockIdx.x;            // 2048 rows
    int row = y[m];
    int t = threadIdx.x;           // 128 threads * float4 = 512 cols
    f4_t v = ((const f4_t*)(emb + (size_t)row * 512))[t];
    us4_t o;
    o[0] = f2bf(v[0]); o[1] = f2bf(v[1]); o[2] = f2bf(v[2]); o[3] = f2bf(v[3]);
    ((us4_t*)(xbf + (size_t)m * 512))[t] = o;
}

// ---------------- h0 = hn @ fc_w.T + fc_b (fp32 master) ----------------
__global__ void k_h0(const float* __restrict__ hn, const float* __restrict__ fc_w,
                     const float* __restrict__ fc_b, float* __restrict__ h0m) {
    __shared__ float sh[1024];
    int b = blockIdx.x, t = threadIdx.x;          // 16 blocks x 256 threads
    for (int i = t; i < 1024; i += 256) sh[i] = hn[b * 1024 + i];
    __syncthreads();
    int j = t;
    float a0 = fc_b[j], a1 = fc_b[j + 256];
    const float* w0 = fc_w + (size_t)j * 1024;
    const float* w1 = fc_w + (size_t)(j + 256) * 1024;
    #pragma unroll 8
    for (int e = 0; e < 1024; e++) { float he = sh[e]; a0 += he * w0[e]; a1 += he * w1[e]; }
    h0m[b * 512 + j] = a0;
    h0m[b * 512 + j + 256] = a1;
}

// ---------------- generic GEMM (used for gx): C = A @ Bt^T + bias ----------------
__launch_bounds__(256)
__global__ void k_gemm(const unsigned short* __restrict__ A, const unsigned short* __restrict__ Bt,
                       const float* __restrict__ bias, float* __restrict__ C, int N) {
    __shared__ unsigned short sA[128 * 64];
    __shared__ unsigned short sB[128 * 64];
    const int m0 = blockIdx.y * 128, n0 = blockIdx.x * 128;
    const int tid = threadIdx.x, lane = tid & 63, wave = tid >> 6;
    const int wm = wave >> 1, wn = wave & 1;
    f4_t acc[4][4] = {};
    for (int ks = 0; ks < 8; ks++) {
        const int k0 = ks * 64;
        #pragma unroll
        for (int t = 0; t < 4; t++) {
            int idx = tid + t * 256;
            int row = idx >> 3, slot = idx & 7;
            int sw = ((slot ^ (row & 7)) << 3);
            *(us8_t*)(&sA[row * 64 + sw]) = *(const us8_t*)(A + (size_t)(m0 + row) * 512 + k0 + slot * 8);
            *(us8_t*)(&sB[row * 64 + sw]) = *(const us8_t*)(Bt + (size_t)(n0 + row) * 512 + k0 + slot * 8);
        }
        __syncthreads();
        #pragma unroll
        for (int kk = 0; kk < 2; kk++) {
            bf8_t af[4], bfr[4];
            #pragma unroll
            for (int mi = 0; mi < 4; mi++) {
                int row = wm * 64 + mi * 16 + (lane & 15);
                int slot = (kk * 4 + (lane >> 4)) ^ (row & 7);
                af[mi] = *(const bf8_t*)(&sA[row * 64 + slot * 8]);
            }
            #pragma unroll
            for (int ni = 0; ni < 4; ni++) {
                int row = wn * 64 + ni * 16 + (lane & 15);
                int slot = (kk * 4 + (lane >> 4)) ^ (row & 7);
                bfr[ni] = *(const bf8_t*)(&sB[row * 64 + slot * 8]);
            }
            #pragma unroll
            for (int mi = 0; mi < 4; mi++)
                #pragma unroll
                for (int ni = 0; ni < 4; ni++)
                    acc[mi][ni] = __builtin_amdgcn_mfma_f32_16x16x32_bf16(af[mi], bfr[ni], acc[mi][ni], 0, 0, 0);
        }
        __syncthreads();
    }
    #pragma unroll
    for (int ni = 0; ni < 4; ni++) {
        int col = n0 + wn * 64 + ni * 16 + (lane & 15);
        float bv = bias[col];
        #pragma unroll
        for (int mi = 0; mi < 4; mi++) {
            int rbase = m0 + wm * 64 + mi * 16 + (lane >> 4) * 4;
            #pragma unroll
            for (int r = 0; r < 4; r++)
                C[(size_t)(rbase + r) * N + col] = acc[mi][ni][r] + bv;
        }
    }
}

// ---------------- fused scan + projection ----------------
// Blocks 0..15: GRU scan (R8 protocol). Blocks 16..255: projection with
// LDS-resident B panel; tn = bid-16 (+ tn 240..249 on bids 16..25, restaged
// per tm). A staged per-ks from HoutP with sentinel poll; per-tm probe gate.
__launch_bounds__(256, 1)
__global__ void k_fused(const float* __restrict__ W_hh, const float* __restrict__ b_hh,
                        const float* __restrict__ gx, const float* __restrict__ h0m,
                        unsigned int* __restrict__ hbuf, unsigned int* __restrict__ HoutP,
                        const unsigned short* __restrict__ pwbf, const float* __restrict__ pred_b,
                        float* __restrict__ out) {
    __shared__ __align__(16) unsigned char smem[131072 + 16384];  // B panel + A ks-buf
    const int tid = threadIdx.x;
    const int lane = tid & 63;
    const int wave = tid >> 6;

    if (blockIdx.x < 16) {
        // ================= scan =================
        float* sPart = (float*)smem;                      // [2][2][12][64]
        const int c = blockIdx.x;
        const int ch = wave >> 1, w = wave & 1;
        const int col = c * 32 + ch * 16 + (lane & 15);
        const int kgrp = lane >> 4, bbase = kgrp * 4;

        bf8_t wfR[8], wfZ[8], wfN[8];
        {
            const f4_t* wr = (const f4_t*)(W_hh + (size_t)col * 512);
            const f4_t* wz = (const f4_t*)(W_hh + (size_t)(512 + col) * 512);
            const f4_t* wn = (const f4_t*)(W_hh + (size_t)(1024 + col) * 512);
            const int fo = kgrp * 2;
            #pragma unroll
            for (int j = 0; j < 8; j++) {
                const int kk = w * 8 + j;
                wfR[j] = mk_frag(wr[kk * 8 + fo], wr[kk * 8 + fo + 1]);
                wfZ[j] = mk_frag(wz[kk * 8 + fo], wz[kk * 8 + fo + 1]);
                wfN[j] = mk_frag(wn[kk * 8 + fo], wn[kk * 8 + fo + 1]);
            }
        }
        float brv = 0.f, bzv = 0.f, bnv = 0.f;
        f4_t h_reg = {0.f, 0.f, 0.f, 0.f};
        if (w == 0) {
            brv = b_hh[col]; bzv = b_hh[512 + col]; bnv = b_hh[1024 + col];
            #pragma unroll
            for (int r = 0; r < 4; r++) h_reg[r] = h0m[(bbase + r) * 512 + col];
            #pragma unroll
            for (int r = 0; r < 4; r++) {
                unsigned int hb = f2bf(h_reg[r]);
                unsigned int pr = __shfl_xor(hb, 1, 64);
                if (!(lane & 1))
                    llc_store_u32(&hbuf[(bbase + r) * 256 + (col >> 1)], hb | (pr << 16));
            }
        }

        for (int s = 1; s <= 128; s++) {
            float gxr[4], gxz[4], gxn[4];
            if (w == 0) {
                #pragma unroll
                for (int r = 0; r < 4; r++) {
                    const float* gp = gx + (size_t)((bbase + r) * 128 + (s - 1)) * 1536 + col;
                    gxr[r] = gp[0]; gxz[r] = gp[512]; gxn[r] = gp[1024];
                }
            }
            // ---- poll own K-half of h[s-1]: loads ARE the A-frags ----
            const unsigned int* base = hbuf + (size_t)(s - 1) * 4096
                                     + (lane & 15) * 256 + kgrp * 4 + w * 128;
            u4_t q[8];
            int spins = 0;
            bool ok;
            do {
                asm volatile(
                    "global_load_dwordx4 %0, %8, off sc0 sc1\n\t"
                    "global_load_dwordx4 %1, %8, off offset:64 sc0 sc1\n\t"
                    "global_load_dwordx4 %2, %8, off offset:128 sc0 sc1\n\t"
                    "global_load_dwordx4 %3, %8, off offset:192 sc0 sc1\n\t"
                    "global_load_dwordx4 %4, %8, off offset:256 sc0 sc1\n\t"
                    "global_load_dwordx4 %5, %8, off offset:320 sc0 sc1\n\t"
                    "global_load_dwordx4 %6, %8, off offset:384 sc0 sc1\n\t"
                    "global_load_dwordx4 %7, %8, off offset:448 sc0 sc1\n\t"
                    "s_waitcnt vmcnt(0)"
                    : "=&v"(q[0]), "=&v"(q[1]), "=&v"(q[2]), "=&v"(q[3]),
                      "=&v"(q[4]), "=&v"(q[5]), "=&v"(q[6]), "=&v"(q[7])
                    : "v"(base)
                    : "memory");
                ok = true;
                #pragma unroll
                for (int j = 0; j < 8; j++)
                    #pragma unroll
                    for (int i = 0; i < 4; i++)
                        ok = ok && (q[j][i] != SENT);
            } while (!__all(ok) && ++spins < (1 << 20));   // hang guard
            __builtin_amdgcn_sched_barrier(0);

            f4_t aR = {}, aZ = {}, aN = {};
            #pragma unroll
            for (int j = 0; j < 8; j++) {
                bf8_t af = __builtin_bit_cast(bf8_t, q[j]);
                aR = __builtin_amdgcn_mfma_f32_16x16x32_bf16(af, wfR[j], aR, 0, 0, 0);
                aZ = __builtin_amdgcn_mfma_f32_16x16x32_bf16(af, wfZ[j], aZ, 0, 0, 0);
                aN = __builtin_amdgcn_mfma_f32_16x16x32_bf16(af, wfN[j], aN, 0, 0, 0);
            }

            const int slot = s & 1;
            if (w == 1) {
                #pragma unroll
                for (int r = 0; r < 4; r++) {
                    sPart[((slot * 2 + ch) * 12 + r) * 64 + lane]     = aR[r];
                    sPart[((slot * 2 + ch) * 12 + 4 + r) * 64 + lane] = aZ[r];
                    sPart[((slot * 2 + ch) * 12 + 8 + r) * 64 + lane] = aN[r];
                }
            }
            __syncthreads();
            if (w == 0) {
                unsigned int hb[4];
                #pragma unroll
                for (int r = 0; r < 4; r++) {
                    float pR = aR[r] + sPart[((slot * 2 + ch) * 12 + r) * 64 + lane];
                    float pZ = aZ[r] + sPart[((slot * 2 + ch) * 12 + 4 + r) * 64 + lane];
                    float pN = aN[r] + sPart[((slot * 2 + ch) * 12 + 8 + r) * 64 + lane];
                    float rr = fsigm(gxr[r] + pR + brv);
                    float zz = fsigm(gxz[r] + pZ + bzv);
                    float nn = ftanh(gxn[r] + rr * (pN + bnv));
                    float hnew = (1.f - zz) * nn + zz * h_reg[r];
                    h_reg[r] = hnew;
                    hb[r] = f2bf(hnew);
                }
                // publish hbuf FIRST (cross-block critical path), then HoutP
                #pragma unroll
                for (int r = 0; r < 4; r++) {
                    unsigned int pr = __shfl_xor(hb[r], 1, 64);
                    if (!(lane & 1))
                        llc_store_u32(&hbuf[(size_t)s * 4096 + (bbase + r) * 256 + (col >> 1)],
                                      hb[r] | (pr << 16));
                }
                #pragma unroll
                for (int r = 0; r < 4; r++) {
                    unsigned int pr = __shfl_xor(hb[r], 1, 64);
                    if (!(lane & 1))
                        llc_store_u32(&HoutP[(size_t)((s - 1) * 16 + bbase + r) * 256 + (col >> 1)],
                                      hb[r] | (pr << 16));
                }
            }
        }
        return;   // scan blocks done; all 250 panels covered by blocks 16..255
    }

    // ================= projection: LDS-resident B panel =================
    unsigned short* sBp = (unsigned short*)smem;              // [128][512] swizzled
    unsigned short* sA  = (unsigned short*)(smem + 131072);   // [128][64] per-ks
    const int wm = wave >> 1, wn = wave & 1;
    const unsigned short* A = (const unsigned short*)HoutP;   // 2048 x 512 bf16, s-major

    const int tnA = blockIdx.x - 16;                          // 0..239
    const int npan = (tnA < 10) ? 2 : 1;                      // bids 16..25 also own 240+tnA

    int rowA[4], slotA[4];
    #pragma unroll
    for (int t4 = 0; t4 < 4; t4++) {
        int idx = tid + t4 * 256;
        rowA[t4] = idx >> 3; slotA[t4] = idx & 7;
    }

    for (int tm = 0; tm < 16; tm++) {
        const int m0 = tm * 128;
        // coarse per-tm gate: last dword of the tm panel's last row
        if (tid == 0) {
            const unsigned int* probe = HoutP + (size_t)(m0 + 127) * 256 + 255;
            unsigned v; int guard = 0;
            do {
                asm volatile("global_load_dword %0, %1, off sc0 sc1\n\ts_waitcnt vmcnt(0)"
                             : "=&v"(v) : "v"(probe) : "memory");
                if (v == SENT) __builtin_amdgcn_s_sleep(16);
            } while (v == SENT && ++guard < (1 << 20));
        }
        __syncthreads();

        for (int pi = 0; pi < npan; pi++) {
            const int tn = (pi == 0) ? tnA : 240 + tnA;
            const int n0 = tn * 128;

            if (tm == 0 || npan == 2) {                       // stage B panel into LDS
                #pragma unroll
                for (int t4 = 0; t4 < 32; t4++) {
                    int idx = tid + t4 * 256;                 // 8192 us8 chunks
                    int row = idx >> 6, slot = idx & 63;
                    *(us8_t*)(&sBp[row * 512 + ((slot ^ (row & 7)) << 3)]) =
                        *(const us8_t*)(pwbf + (size_t)(n0 + row) * 512 + slot * 8);
                }
            }
            __syncthreads();                                  // B visible to all waves

            f4_t acc[4][4] = {};
            for (int ks = 0; ks < 8; ks++) {
                const int k0 = ks * 64;
                // A staging with sentinel poll (covers stragglers past the probe)
                {
                    const unsigned short* p0 = A + (size_t)(m0 + rowA[0]) * 512 + k0 + slotA[0] * 8;
                    const unsigned short* p1 = A + (size_t)(m0 + rowA[1]) * 512 + k0 + slotA[1] * 8;
                    const unsigned short* p2 = A + (size_t)(m0 + rowA[2]) * 512 + k0 + slotA[2] * 8;
                    const unsigned short* p3 = A + (size_t)(m0 + rowA[3]) * 512 + k0 + slotA[3] * 8;
                    u4_t a0, a1, a2, a3;
                    int spins = 0; bool okk;
                    do {
                        asm volatile(
                            "global_load_dwordx4 %0, %4, off sc0 sc1\n\t"
                            "global_load_dwordx4 %1, %5, off sc0 sc1\n\t"
                            "global_load_dwordx4 %2, %6, off sc0 sc1\n\t"
                            "global_load_dwordx4 %3, %7, off sc0 sc1\n\t"
                            "s_waitcnt vmcnt(0)"
                            : "=&v"(a0), "=&v"(a1), "=&v"(a2), "=&v"(a3)
                            : "v"(p0), "v"(p1), "v"(p2), "v"(p3)
                            : "memory");
                        okk = true;
                        #pragma unroll
                        for (int i = 0; i < 4; i++)
                            okk = okk && (a0[i] != SENT) && (a1[i] != SENT)
                                      && (a2[i] != SENT) && (a3[i] != SENT);
                        if (!okk) __builtin_amdgcn_s_sleep(1);
                    } while (!okk && ++spins < (1 << 20));
                    __builtin_amdgcn_sched_barrier(0);
                    *(u4_t*)(&sA[rowA[0] * 64 + ((slotA[0] ^ (rowA[0] & 7)) << 3)]) = a0;
                    *(u4_t*)(&sA[rowA[1] * 64 + ((slotA[1] ^ (rowA[1] & 7)) << 3)]) = a1;
                    *(u4_t*)(&sA[rowA[2] * 64 + ((slotA[2] ^ (rowA[2] & 7)) << 3)]) = a2;
                    *(u4_t*)(&sA[rowA[3] * 64 + ((slotA[3] ^ (rowA[3] & 7)) << 3)]) = a3;
                }
                __syncthreads();
                #pragma unroll
                for (int kk = 0; kk < 2; kk++) {
                    bf8_t af[4], bfr[4];
                    #pragma unroll
                    for (int mi = 0; mi < 4; mi++) {
                        int row = wm * 64 + mi * 16 + (lane & 15);
                        int slot = (kk * 4 + (lane >> 4)) ^ (row & 7);
                        af[mi] = *(const bf8_t*)(&sA[row * 64 + slot * 8]);
                    }
                    #pragma unroll
                    for (int ni = 0; ni < 4; ni++) {
                        int row = wn * 64 + ni * 16 + (lane & 15);
                        int slot = (ks * 8 + kk * 4 + (lane >> 4)) ^ (row & 7);
                        bfr[ni] = *(const bf8_t*)(&sBp[row * 512 + slot * 8]);
                    }
                    #pragma unroll
                    for (int mi = 0; mi < 4; mi++)
                        #pragma unroll
                        for (int ni = 0; ni < 4; ni++)
                            acc[mi][ni] = __builtin_amdgcn_mfma_f32_16x16x32_bf16(af[mi], bfr[ni], acc[mi][ni], 0, 0, 0);
                }
                __syncthreads();
            }
            // epilogue: rows are s-major (m = t16*16+b) -> out[b][t] order
            #pragma unroll
            for (int ni = 0; ni < 4; ni++) {
                int colI = n0 + wn * 64 + ni * 16 + (lane & 15);
                float bv = pred_b[colI];
                #pragma unroll
                for (int mi = 0; mi < 4; mi++) {
                    int rbase = m0 + wm * 64 + mi * 16 + (lane >> 4) * 4;
                    #pragma unroll
                    for (int r = 0; r < 4; r++) {
                        int mr = rbase + r;
                        out[(size_t)((mr & 15) * 128 + (mr >> 4)) * 32000 + colI] = acc[mi][ni][r] + bv;
                    }
                }
            }
        }
    }
}

extern "C" void kernel_launch(void* const* d_in, const int* in_sizes, int n_in,
                              void* d_out, int out_size, void* d_ws, size_t ws_size,
                              hipStream_t stream) {
    const int*   y      = (const int*)  d_in[0];
    const float* hn     = (const float*)d_in[1];
    const float* emb    = (const float*)d_in[2];
    const float* W_ih   = (const float*)d_in[3];
    const float* W_hh   = (const float*)d_in[4];
    const float* b_ih   = (const float*)d_in[5];
    const float* b_hh   = (const float*)d_in[6];
    const float* fc_w   = (const float*)d_in[7];
    const float* fc_b   = (const float*)d_in[8];
    const float* pred_w = (const float*)d_in[9];
    const float* pred_b = (const float*)d_in[10];
    float* out = (float*)d_out;

    char* ws = (char*)d_ws;
    size_t off = 0;
    auto alloc = [&](size_t bytes) { void* p = ws + off; off = (off + bytes + 255) & ~(size_t)255; return p; };
    unsigned int*   hbuf   = (unsigned int*)   alloc((size_t)129 * 4096 * 4);  // packed bf16 h, per step
    unsigned int*   HoutP  = (unsigned int*)   alloc((size_t)2048 * 256 * 4);  // packed bf16, s-major
    float*          h0m    = (float*)          alloc((size_t)16 * 512 * 4);    // fp32 h0 master
    float*          gx     = (float*)          alloc((size_t)2048 * 1536 * 4);
    unsigned short* xbf    = (unsigned short*) alloc((size_t)2048 * 512 * 2);
    unsigned short* wihbf  = (unsigned short*) alloc((size_t)1536 * 512 * 2);
    unsigned short* pwbf   = (unsigned short*) alloc((size_t)32000 * 512 * 2);
    (void)ws_size; (void)in_sizes; (void)n_in; (void)out_size;                 // ~54 MB used

    k_fill  <<<1028, 256, 0, stream>>>(hbuf, HoutP);                // 263168 u4s
    k_conv  <<<4096, 256, 0, stream>>>(pred_w, pwbf, 32000 * 512 / 4);
    k_conv  <<<512,  256, 0, stream>>>(W_ih,  wihbf, 1536 * 512 / 4);
    k_gather<<<2048, 128, 0, stream>>>(y, emb, xbf);
    k_h0    <<<16,   256, 0, stream>>>(hn, fc_w, fc_b, h0m);
    dim3 gG(12, 16);
    k_gemm  <<<gG, 256, 0, stream>>>(xbf, wihbf, b_ih, gx, 1536);
    k_fused <<<256, 256, 0, stream>>>(W_hh, b_hh, gx, h0m, hbuf, HoutP,
                                      pwbf, pred_b, out);
}